// Round 3
// baseline (333.377 us; speedup 1.0000x reference)
//
#include <hip/hip_runtime.h>
#include <hip/hip_fp16.h>

// Problem constants (hard-coded from reference: LEVELS, heads, dims)
// Dtype model: fp32 buffers, values on f16 grid -> f16 MFMA (more precise
// than bf16 for this data; all magnitudes << f16 range).
#define BS 2
#define NQ 21760
#define NV 21760
#define DIM 256
#define NH 8
#define DH 32
#define NL 4
#define NP 4

typedef __attribute__((ext_vector_type(8))) _Float16 f16x8;
typedef __attribute__((ext_vector_type(4))) float f32x4;

__device__ __forceinline__ unsigned short f2h(float f) {
    return __half_as_ushort(__float2half(f));   // v_cvt_f16_f32 (RNE)
}
__device__ __forceinline__ float h2f(unsigned short s) {
    return __half2float(__ushort_as_half(s));
}

// ---------------------------------------------------------------------------
// W prep: weights -> f16, pre-swizzled into MFMA B-fragment order.
// Tile (nb,kb) = 64 lanes x 8 f16, contiguous 1 KB.
// Regions: [qo: Wo(16nb)|Wa(8nb)][v: Wv 16nb][out: Wout 16nb], 8 kb each.
// ---------------------------------------------------------------------------
__global__ __launch_bounds__(64) void k_wprep(
    const float* __restrict__ Wo, const float* __restrict__ Wa,
    const float* __restrict__ Wv, const float* __restrict__ Wout,
    unsigned short* __restrict__ wsw)
{
    const int tile = blockIdx.x;
    const int lane = threadIdx.x;
    const float* W; int N, nb, kb;
    if (tile < 192) { nb = tile >> 3; kb = tile & 7;
        if (nb < 16) { W = Wo; N = 256; } else { W = Wa; N = 128; nb -= 16; } }
    else if (tile < 320) { int tt = tile - 192; nb = tt >> 3; kb = tt & 7; W = Wv;   N = 256; }
    else               { int tt = tile - 320; nb = tt >> 3; kb = tt & 7; W = Wout; N = 256; }
    const int quad = lane >> 4, l15 = lane & 15;
    const int col = nb * 16 + l15;
    unsigned int pk[4];
#pragma unroll
    for (int jj = 0; jj < 4; jj++) {
        int k0 = kb * 32 + quad * 8 + jj * 2;
        pk[jj] = (unsigned int)f2h(W[(size_t)k0 * N + col])
               | ((unsigned int)f2h(W[(size_t)(k0 + 1) * N + col]) << 16);
    }
    *(uint4*)(wsw + (size_t)tile * 512 + lane * 8) = *(const uint4*)pk;
}

// Stage 64 rows x 256 cols fp32 -> LDS f16 (row pitch 264 = +8 pad). 512 thr.
__device__ __forceinline__ void stage_f32_512(const float* __restrict__ src,
                                              unsigned short* __restrict__ As)
{
    const int t = threadIdx.x;
    const int colg = t & 63;
    const int row0 = t >> 6;
#pragma unroll
    for (int i = 0; i < 8; i++) {
        int row = row0 + i * 8;
        float4 f = ((const float4*)(src + (size_t)row * 256))[colg];
        uint2 p;
        p.x = (unsigned int)f2h(f.x) | ((unsigned int)f2h(f.y) << 16);
        p.y = (unsigned int)f2h(f.z) | ((unsigned int)f2h(f.w) << 16);
        *(uint2*)&As[row * 264 + colg * 4] = p;
    }
}

__device__ __forceinline__ void stage_h16_512(const unsigned short* __restrict__ src,
                                              unsigned short* __restrict__ As)
{
    const int t = threadIdx.x;
    const int colg = t & 63;
    const int row0 = t >> 6;
#pragma unroll
    for (int i = 0; i < 8; i++) {
        int row = row0 + i * 8;
        uint2 u = ((const uint2*)(src + (size_t)row * 256))[colg];
        *(uint2*)&As[row * 264 + colg * 4] = u;
    }
}

// Split GEMM core v2: 512 thr = 8 waves; wave w -> row group (w&1)*32 (TWO
// 16-row A fragments), col quarter (w>>1). Each B-fragment load feeds 2 MFMAs.
template<int NBH>
__device__ __forceinline__ void gemm_split2(const unsigned short* __restrict__ As,
                                            const unsigned short* __restrict__ wswb,
                                            f32x4* acc)   // [2][NBH] flattened
{
    const int t = threadIdx.x;
    const int w = t >> 6, lane = t & 63;
    const int wr = w & 1, wg = w >> 1;
    const int quad = lane >> 4, l15 = lane & 15;
    const int ra0 = (wr * 32 + l15) * 264;
#pragma unroll
    for (int kb = 0; kb < 8; kb++) {
        f16x8 af0 = *(const f16x8*)&As[ra0 + kb * 32 + quad * 8];
        f16x8 af1 = *(const f16x8*)&As[ra0 + 16 * 264 + kb * 32 + quad * 8];
#pragma unroll
        for (int nbi = 0; nbi < NBH; nbi++) {
            const int nb = wg * NBH + nbi;
            f16x8 bf = *(const f16x8*)(wswb + (((nb * 8 + kb) << 9) + (lane << 3)));
            acc[nbi]       = __builtin_amdgcn_mfma_f32_16x16x32_f16(af0, bf, acc[nbi], 0, 0, 0);
            acc[NBH + nbi] = __builtin_amdgcn_mfma_f32_16x16x32_f16(af1, bf, acc[NBH + nbi], 0, 0, 0);
        }
    }
}

// K1: fused projections. Blocks [0,680): v = value@Wv+bv -> f16 head-major
//   v_hm[((b*NH+h)*NV + pix)*DH + ch]; epilogue transposes through LDS so
//   v_hm stores are coalesced 8B (was 32 scattered 2B stores per thread).
// Blocks [680,1360): offs=q@Wo+bo -> locs (fp32); attw=softmax(q@Wa+ba) -> f16.
__global__ __launch_bounds__(512) void k_proj(
    const float* __restrict__ value,
    const float* __restrict__ query,
    const float* __restrict__ refp,
    const unsigned short* __restrict__ wsw,
    const float* __restrict__ bv,
    const float* __restrict__ bo,
    const float* __restrict__ ba,
    unsigned short* __restrict__ v_hm,
    float* __restrict__ locs_ws,
    unsigned short* __restrict__ attw_b)
{
    __shared__ unsigned short As[64 * 264];
    const int t = threadIdx.x;
    const int w = t >> 6, lane = t & 63;
    const int wr = w & 1, wg = w >> 1;
    const int quad = lane >> 4, l15 = lane & 15;

    if (blockIdx.x < 680) {
        const size_t r0 = (size_t)blockIdx.x * 64;
        const int bb = (blockIdx.x >= 340);             // 340 blocks per batch (NV = 340*64)
        const int pix0 = (int)(r0 - (size_t)bb * NV);
        stage_f32_512(value + r0 * 256, As);
        __syncthreads();
        f32x4 acc[8];                                   // [2][4]
#pragma unroll
        for (int i = 0; i < 8; i++) acc[i] = (f32x4){0.f, 0.f, 0.f, 0.f};
        gemm_split2<4>(As, wsw + 98304, acc);
        // epilogue: acc -> As transposed [pixL][col] f16, then coalesced out
        __syncthreads();
#pragma unroll
        for (int rf = 0; rf < 2; rf++) {
#pragma unroll
            for (int nbi = 0; nbi < 4; nbi++) {
                const int col = (wg * 4 + nbi) * 16 + l15;
                const float bias = bv[col];
#pragma unroll
                for (int r = 0; r < 4; r++) {
                    int pixL = wr * 32 + rf * 16 + quad * 4 + r;
                    As[pixL * 264 + col] = f2h(acc[rf * 4 + nbi][r] + bias);
                }
            }
        }
        __syncthreads();
        const int pix = t >> 3, c8 = t & 7;
#pragma unroll
        for (int hh = 0; hh < 8; hh++) {
            uint2 d = *(const uint2*)&As[pix * 264 + hh * 32 + c8 * 4];
            *(uint2*)(v_hm + (((size_t)bb * NH + hh) * NV + pix0 + pix) * DH + c8 * 4) = d;
        }
    } else {
        const size_t r0 = (size_t)(blockIdx.x - 680) * 64;
        stage_f32_512(query + r0 * 256, As);
        __syncthreads();
        f32x4 acc[12];                                  // [2][6]
#pragma unroll
        for (int i = 0; i < 12; i++) acc[i] = (f32x4){0.f, 0.f, 0.f, 0.f};
        gemm_split2<6>(As, wsw, acc);
#pragma unroll
        for (int rf = 0; rf < 2; rf++) {
#pragma unroll
            for (int nbi = 0; nbi < 6; nbi++) {
                const int nb = wg * 6 + nbi;
                const int rowoff = wr * 32 + rf * 16 + quad * 4;
                if (nb < 16) {
                    // offs -> sampling locations. col -> (h,l,p,xy), norm=128>>l.
                    const int col = nb * 16 + l15;
                    const int l = (col >> 3) & 3;
                    const int xy = col & 1;
                    const float rnorm = 1.f / (float)(128 >> l);
                    const float bo_c = bo[col];
#pragma unroll
                    for (int r = 0; r < 4; r++) {
                        size_t row = r0 + rowoff + r;
                        float ref = refp[row * 8 + l * 2 + xy];
                        locs_ws[row * 256 + col] = ref + (acc[rf * 6 + nbi][r] + bo_c) * rnorm;
                    }
                } else {
                    // attw: softmax over 16-lane groups (bits 0-3) -> f16
                    const int col = (nb - 16) * 16 + l15;
                    const float ba_c = ba[col];
#pragma unroll
                    for (int r = 0; r < 4; r++) {
                        float v = acc[rf * 6 + nbi][r] + ba_c;
                        float m = v;
                        m = fmaxf(m, __shfl_xor(m, 1, 64));
                        m = fmaxf(m, __shfl_xor(m, 2, 64));
                        m = fmaxf(m, __shfl_xor(m, 4, 64));
                        m = fmaxf(m, __shfl_xor(m, 8, 64));
                        float e = __expf(v - m);
                        float s = e;
                        s += __shfl_xor(s, 1, 64);
                        s += __shfl_xor(s, 2, 64);
                        s += __shfl_xor(s, 4, 64);
                        s += __shfl_xor(s, 8, 64);
                        size_t row = r0 + rowoff + r;
                        attw_b[row * 128 + col] = f2h(e / s);
                    }
                }
            }
        }
    }
}

__device__ __forceinline__ void acc4(float wf, uint2 d,
                                     float& a0, float& a1, float& a2, float& a3)
{
    // f16 -> f32 convert feeding fma fuses to v_fma_mix_f32 (no unpack insts)
    __half2 lo = *(__half2*)&d.x;
    __half2 hi = *(__half2*)&d.y;
    a0 = fmaf(wf, __half2float(__low2half(lo)),  a0);
    a1 = fmaf(wf, __half2float(__high2half(lo)), a1);
    a2 = fmaf(wf, __half2float(__low2half(hi)),  a2);
    a3 = fmaf(wf, __half2float(__high2half(hi)), a3);
}

// K2: fused tap-build + bilinear sampling. Block = one (b,h) x 32 queries;
// 256 thr (4 waves). Grid 10880 = 8 XCD x 2 head-slices x 680 chunks; bid&7
// pins each (b,h) pair's 1.39 MB f16 slice to one XCD L2.
// Phase 1: 512 taps x 4 corners {w, pix*64} into LDS, layout [tp][corner][q]
//   (conflict-free for both the q-strided writes and q-indexed reads).
// Phase 2: lane = q(3b)|c4(3b) -- each lane OWNS one query's channel quad and
//   accumulates all 64 (tap,corner) gathers itself: zero cross-lane reduction
//   (r2 spent 12 shfl + 12 add per q), one store-inst per wave, and fma_mix
//   consumes f16 directly (r2 spent 32 unpack VALU per q). Segments/q stay 64
//   (the r1-vs-r2 invariant) -- this attacks the issue-side cost only.
__global__ __launch_bounds__(256) void k_sample(
    const unsigned short* __restrict__ v_hm,
    const float* __restrict__ locs_ws,
    const unsigned short* __restrict__ attw_b,
    unsigned short* __restrict__ msda_ws)
{
    __shared__ uint2 tap[16 * 4 * 32];   // [tp][corner][q] = {w_f32, pix*64}
    const int t = threadIdx.x;
    const int bid = blockIdx.x;

    const int xcd  = bid & 7;
    const int slot = bid >> 3;                 // [0,1360)
    const int sub  = (slot >= 680) ? 1 : 0;
    const int chunk = slot - sub * 680;        // [0,680)
    const int pair = xcd * 2 + sub;            // [0,16)
    const int b = pair & 1;
    const int h = pair >> 1;
    const int q0 = chunk * 32;

    // ---- Phase 1: tap build. tapid = tp*32 + q (q fast -> conflict-free LDS
    // writes; locs reads scatter 8B x 32 rows, negligible vs phase-2 volume).
#pragma unroll
    for (int i = 0; i < 2; i++) {
        const int tapid = t + i * 256;         // [0,512)
        const int q  = tapid & 31;             // local q [0,32)
        const int tp = tapid >> 5;             // (l,p)
        const size_t row = (size_t)(b * NQ + q0 + q);
        float2 xy = *(const float2*)(locs_ws + row * 256 + h * 32 + tp * 2);
        float a   = h2f(attw_b[row * 128 + h * 16 + tp]);

        const int l = tp >> 2;
        const int Wl = 128 >> l;
        const float Wf = (float)Wl;
        const int start = (l == 0) ? 0 : (l == 1) ? 16384 : (l == 2) ? 20480 : 21504;
        float x = xy.x * Wf - 0.5f;
        float y = xy.y * Wf - 0.5f;
        float xf = floorf(x), yf = floorf(y);
        int x0 = (int)xf, y0 = (int)yf;
        float wx1 = x - xf, wy1 = y - yf;
        float wx0 = 1.f - wx1, wy0 = 1.f - wy1;
#pragma unroll
        for (int c = 0; c < 4; c++) {
            const int dx = c & 1, dy = c >> 1;
            int xi = x0 + dx, yi = y0 + dy;
            bool valid = (xi >= 0) & (xi < Wl) & (yi >= 0) & (yi < Wl);
            int xc = min(max(xi, 0), Wl - 1);
            int yc = min(max(yi, 0), Wl - 1);
            float wc = valid ? a * (dx ? wx1 : wx0) * (dy ? wy1 : wy0) : 0.f;
            uint2 rec;
            rec.x = __float_as_uint(wc);
            rec.y = ((unsigned int)(start + yc * Wl + xc)) * 64u;  // f16 row = 64 B
            tap[(tp * 4 + c) * 32 + q] = rec;
        }
    }
    __syncthreads();

    // ---- Phase 2: lane owns (q, channel-quad); accumulate all 64 gathers.
    const int w4   = t >> 6;
    const int lane = t & 63;
    const int ql   = lane >> 3;
    const int c4   = lane & 7;
    const int q    = w4 * 8 + ql;
    const unsigned int c4off = (unsigned int)c4 * 8u;
    const char* __restrict__ vb =
        (const char*)(v_hm + (size_t)(b * NH + h) * NV * DH);

    float a0 = 0.f, a1 = 0.f, a2 = 0.f, a3 = 0.f;
#pragma unroll
    for (int ti = 0; ti < 16; ti++) {
        uint2 r0 = tap[(ti * 4 + 0) * 32 + q];
        uint2 r1 = tap[(ti * 4 + 1) * 32 + q];
        uint2 r2 = tap[(ti * 4 + 2) * 32 + q];
        uint2 r3 = tap[(ti * 4 + 3) * 32 + q];
        uint2 d0 = *(const uint2*)(vb + (r0.y + c4off));
        uint2 d1 = *(const uint2*)(vb + (r1.y + c4off));
        uint2 d2 = *(const uint2*)(vb + (r2.y + c4off));
        uint2 d3 = *(const uint2*)(vb + (r3.y + c4off));
        acc4(__uint_as_float(r0.x), d0, a0, a1, a2, a3);
        acc4(__uint_as_float(r1.x), d1, a0, a1, a2, a3);
        acc4(__uint_as_float(r2.x), d2, a0, a1, a2, a3);
        acc4(__uint_as_float(r3.x), d3, a0, a1, a2, a3);
    }
    uint2 o;
    o.x = (unsigned int)f2h(a0) | ((unsigned int)f2h(a1) << 16);
    o.y = (unsigned int)f2h(a2) | ((unsigned int)f2h(a3) << 16);
    *(uint2*)(msda_ws + (size_t)(b * NQ + q0 + q) * DIM + h * DH + c4 * 4) = o;
}

// K3: out = msda @ Wout + bout + query -> fp32. 64 rows/block, 512 thr.
__global__ __launch_bounds__(512) void k_out_mfma(
    const unsigned short* __restrict__ msda_ws,
    const unsigned short* __restrict__ wswo,
    const float* __restrict__ bout,
    const float* __restrict__ query,
    float* __restrict__ out)
{
    __shared__ unsigned short As[64 * 264];
    const size_t r0 = (size_t)blockIdx.x * 64;
    stage_h16_512(msda_ws + r0 * 256, As);
    __syncthreads();

    f32x4 acc[8];                                       // [2][4]
#pragma unroll
    for (int i = 0; i < 8; i++) acc[i] = (f32x4){0.f, 0.f, 0.f, 0.f};
    gemm_split2<4>(As, wswo, acc);

    const int t = threadIdx.x;
    const int w = t >> 6, lane = t & 63;
    const int wr = w & 1, wg = w >> 1;
    const int quad = lane >> 4, l15 = lane & 15;
#pragma unroll
    for (int rf = 0; rf < 2; rf++) {
#pragma unroll
        for (int nbi = 0; nbi < 4; nbi++) {
            const int col = (wg * 4 + nbi) * 16 + l15;
            const float bias = bout[col];
#pragma unroll
            for (int r = 0; r < 4; r++) {
                size_t row = r0 + wr * 32 + rf * 16 + quad * 4 + r;
                out[row * 256 + col] = acc[rf * 4 + nbi][r] + bias + query[row * 256 + col];
            }
        }
    }
}

extern "C" void kernel_launch(void* const* d_in, const int* in_sizes, int n_in,
                              void* d_out, int out_size, void* d_ws, size_t ws_size,
                              hipStream_t stream)
{
    const float* query = (const float*)d_in[0];
    const float* value = (const float*)d_in[1];
    const float* refp  = (const float*)d_in[2];
    // d_in[3] spatial_shapes, d_in[4] level_start_index : values hard-coded
    const float* Wv   = (const float*)d_in[5];
    const float* bv   = (const float*)d_in[6];
    const float* Wo   = (const float*)d_in[7];
    const float* bo   = (const float*)d_in[8];
    const float* Wa   = (const float*)d_in[9];
    const float* ba   = (const float*)d_in[10];
    const float* Wout = (const float*)d_in[11];
    const float* bout = (const float*)d_in[12];
    float* out = (float*)d_out;

    char* ws = (char*)d_ws;
    unsigned short* v_hm = (unsigned short*)ws;    ws += (size_t)BS * NH * NV * DH * 2; // 22.3 MB f16 head-major
    float* locs_ws = (float*)ws;                   ws += (size_t)BS * NQ * DIM * 4;     // 44.6 MB fp32
    unsigned short* attw_b = (unsigned short*)ws;  ws += (size_t)BS * NQ * 128 * 2;     // 11.1 MB f16
    unsigned short* msda_ws = (unsigned short*)ws; ws += (size_t)BS * NQ * DIM * 2;     // 22.3 MB f16
    unsigned short* wsw = (unsigned short*)ws;                                          // 448 KB

    k_wprep   <<<448, 64,  0, stream>>>(Wo, Wa, Wv, Wout, wsw);
    k_proj    <<<1360, 512, 0, stream>>>(value, query, refp, wsw, bv, bo, ba,
                                         v_hm, locs_ws, attw_b);
    k_sample  <<<10880, 256, 0, stream>>>(v_hm, locs_ws, attw_b, msda_ws);
    k_out_mfma<<<680, 512, 0, stream>>>(msda_ws, wsw + 163840, bout, query, out);
}

// Round 4
// 304.177 us; speedup vs baseline: 1.0960x; 1.0960x over previous
//
#include <hip/hip_runtime.h>
#include <hip/hip_fp16.h>

// Problem constants (hard-coded from reference: LEVELS, heads, dims)
// Dtype model: fp32 buffers, values on f16 grid -> f16 MFMA.
#define BS 2
#define NQ 21760
#define NV 21760
#define DIM 256
#define NH 8
#define DH 32
#define NL 4
#define NP 4

typedef __attribute__((ext_vector_type(8))) _Float16 f16x8;
typedef __attribute__((ext_vector_type(4))) float f32x4;

__device__ __forceinline__ unsigned short f2h(float f) {
    return __half_as_ushort(__float2half(f));   // v_cvt_f16_f32 (RNE)
}
__device__ __forceinline__ float h2f(unsigned short s) {
    return __half2float(__ushort_as_half(s));
}

// ---------------------------------------------------------------------------
// W prep: weights -> f16, pre-swizzled into MFMA fragment order (layout is
// identical for A- and B-operand use on gfx950: lane&15 = row/col, k =
// (lane>>4)*8+j). Tile (nb,kb) = 64 lanes x 8 f16, contiguous 1 KB.
// Regions: [qo: Wo(16nb)|Wa(8nb)][v: Wv 16nb][out: Wout 16nb], 8 kb each.
// ---------------------------------------------------------------------------
__global__ __launch_bounds__(64) void k_wprep(
    const float* __restrict__ Wo, const float* __restrict__ Wa,
    const float* __restrict__ Wv, const float* __restrict__ Wout,
    unsigned short* __restrict__ wsw)
{
    const int tile = blockIdx.x;
    const int lane = threadIdx.x;
    const float* W; int N, nb, kb;
    if (tile < 192) { nb = tile >> 3; kb = tile & 7;
        if (nb < 16) { W = Wo; N = 256; } else { W = Wa; N = 128; nb -= 16; } }
    else if (tile < 320) { int tt = tile - 192; nb = tt >> 3; kb = tt & 7; W = Wv;   N = 256; }
    else               { int tt = tile - 320; nb = tt >> 3; kb = tt & 7; W = Wout; N = 256; }
    const int quad = lane >> 4, l15 = lane & 15;
    const int col = nb * 16 + l15;
    unsigned int pk[4];
#pragma unroll
    for (int jj = 0; jj < 4; jj++) {
        int k0 = kb * 32 + quad * 8 + jj * 2;
        pk[jj] = (unsigned int)f2h(W[(size_t)k0 * N + col])
               | ((unsigned int)f2h(W[(size_t)(k0 + 1) * N + col]) << 16);
    }
    *(uint4*)(wsw + (size_t)tile * 512 + lane * 8) = *(const uint4*)pk;
}

// ---- Staging helpers: 64 rows x 256 cols -> LDS f16 [64][264] (+8 pad) ----
__device__ __forceinline__ void stage_f32_512(const float* __restrict__ src,
                                              unsigned short* __restrict__ As)
{
    const int t = threadIdx.x;
    const int colg = t & 63;
    const int row0 = t >> 6;
#pragma unroll
    for (int i = 0; i < 8; i++) {
        int row = row0 + i * 8;
        float4 f = ((const float4*)(src + (size_t)row * 256))[colg];
        uint2 p;
        p.x = (unsigned int)f2h(f.x) | ((unsigned int)f2h(f.y) << 16);
        p.y = (unsigned int)f2h(f.z) | ((unsigned int)f2h(f.w) << 16);
        *(uint2*)&As[row * 264 + colg * 4] = p;
    }
}
__device__ __forceinline__ void pf_load_f32(const float* __restrict__ src, float4* pf)
{
    const int t = threadIdx.x;
    const int colg = t & 63;
    const int row0 = t >> 6;
#pragma unroll
    for (int i = 0; i < 8; i++)
        pf[i] = ((const float4*)(src + (size_t)(row0 + i * 8) * 256))[colg];
}
__device__ __forceinline__ void pf_store_f32(const float4* pf, unsigned short* __restrict__ As)
{
    const int t = threadIdx.x;
    const int colg = t & 63;
    const int row0 = t >> 6;
#pragma unroll
    for (int i = 0; i < 8; i++) {
        uint2 p;
        p.x = (unsigned int)f2h(pf[i].x) | ((unsigned int)f2h(pf[i].y) << 16);
        p.y = (unsigned int)f2h(pf[i].z) | ((unsigned int)f2h(pf[i].w) << 16);
        *(uint2*)&As[(row0 + i * 8) * 264 + colg * 4] = p;
    }
}
__device__ __forceinline__ void stage_h16_512(const unsigned short* __restrict__ src,
                                              unsigned short* __restrict__ As)
{
    const int t = threadIdx.x;
    const int colg = t & 63;
    const int row0 = t >> 6;
#pragma unroll
    for (int i = 0; i < 8; i++) {
        int row = row0 + i * 8;
        uint2 u = ((const uint2*)(src + (size_t)row * 256))[colg];
        *(uint2*)&As[row * 264 + colg * 4] = u;
    }
}
__device__ __forceinline__ void pf_load_h16(const unsigned short* __restrict__ src, uint2* pf)
{
    const int t = threadIdx.x;
    const int colg = t & 63;
    const int row0 = t >> 6;
#pragma unroll
    for (int i = 0; i < 8; i++)
        pf[i] = ((const uint2*)(src + (size_t)(row0 + i * 8) * 256))[colg];
}
__device__ __forceinline__ void pf_store_h16(const uint2* pf, unsigned short* __restrict__ As)
{
    const int t = threadIdx.x;
    const int colg = t & 63;
    const int row0 = t >> 6;
#pragma unroll
    for (int i = 0; i < 8; i++)
        *(uint2*)&As[(row0 + i * 8) * 264 + colg * 4] = pf[i];
}

// Swapped-operand MFMA core: A = resident weight fragments (M m-tiles of 16
// wcols), B = staged data rows (4 n-tiles of 16 rows). C: lane col(l15)=data
// row, C row(quad*4+r)=wcol -> per-lane outputs are 4 CONSECUTIVE wcols.
template<int M>
__device__ __forceinline__ void mfma_resident(const unsigned short* __restrict__ As,
                                              const f16x8 aw[][8], f32x4 acc[][4],
                                              int lane)
{
    const int quad = lane >> 4, l15 = lane & 15;
#pragma unroll
    for (int kb = 0; kb < 8; kb++) {
        f16x8 dq[4];
#pragma unroll
        for (int n = 0; n < 4; n++)
            dq[n] = *(const f16x8*)&As[(n * 16 + l15) * 264 + kb * 32 + quad * 8];
#pragma unroll
        for (int m = 0; m < M; m++)
#pragma unroll
            for (int n = 0; n < 4; n++)
                acc[m][n] = __builtin_amdgcn_mfma_f32_16x16x32_f16(aw[m][kb], dq[n], acc[m][n], 0, 0, 0);
    }
}

// K1: fused projections, persistent weights. 680 blocks x 512 thr, 2 row-tiles
// each. Blocks [0,340): v = value@Wv+bv -> f16 head-major v_hm; wave w = head
// w (wcols [w*32,(w+1)*32)), epilogue = 8x8B direct stores. Blocks [340,680):
// q@{Wo|Wa}: wave w owns wcols [w*48,w*48+48); offs -> float4 locs stores
// (+float2 refp reads), attw softmax over quad(shfl16/32)xreg -> 8B stores.
// Weight fragments live in VGPRs for both tiles (L2 weight traffic /4);
// tile-2 data is register-prefetched during tile-1 compute (T14).
__global__ __launch_bounds__(512) void k_proj(
    const float* __restrict__ value,
    const float* __restrict__ query,
    const float* __restrict__ refp,
    const unsigned short* __restrict__ wsw,
    const float* __restrict__ bv,
    const float* __restrict__ bo,
    const float* __restrict__ ba,
    unsigned short* __restrict__ v_hm,
    float* __restrict__ locs_ws,
    unsigned short* __restrict__ attw_b)
{
    __shared__ unsigned short As[64 * 264];
    const int t = threadIdx.x;
    const int w = t >> 6, lane = t & 63;
    const int quad = lane >> 4, l15 = lane & 15;

    if (blockIdx.x < 340) {
        const int tb = blockIdx.x * 2;
        // resident Wv fragments: m-tiles {2w, 2w+1} = head w
        f16x8 aw[2][8];
        const unsigned short* wvb = wsw + 98304;
#pragma unroll
        for (int m = 0; m < 2; m++)
#pragma unroll
            for (int kb = 0; kb < 8; kb++)
                aw[m][kb] = *(const f16x8*)(wvb + ((((w * 2 + m) * 8 + kb) << 9) + (lane << 3)));
        float4 bias[2];
#pragma unroll
        for (int m = 0; m < 2; m++)
            bias[m] = *(const float4*)(bv + w * 32 + m * 16 + quad * 4);

        stage_f32_512(value + (size_t)tb * 64 * 256, As);
        __syncthreads();
        float4 pf[8];
        pf_load_f32(value + (size_t)(tb + 1) * 64 * 256, pf);

#pragma unroll
        for (int tt = 0; tt < 2; tt++) {
            const int tg = tb + tt;
            const int bb = (tg >= 340);
            const int pix0 = tg * 64 - bb * NV;
            f32x4 acc[2][4];
#pragma unroll
            for (int m = 0; m < 2; m++)
#pragma unroll
                for (int n = 0; n < 4; n++) acc[m][n] = (f32x4){0.f, 0.f, 0.f, 0.f};
            mfma_resident<2>(As, aw, acc, lane);
            // epilogue: lane -> (pix = pix0+n*16+l15, ch = m*16+quad*4), head w
            unsigned short* __restrict__ vh =
                v_hm + ((size_t)(bb * NH + w) * NV + pix0) * DH;
#pragma unroll
            for (int m = 0; m < 2; m++)
#pragma unroll
                for (int n = 0; n < 4; n++) {
                    f32x4 a = acc[m][n];
                    uint2 o;
                    o.x = (unsigned int)f2h(a[0] + bias[m].x)
                        | ((unsigned int)f2h(a[1] + bias[m].y) << 16);
                    o.y = (unsigned int)f2h(a[2] + bias[m].z)
                        | ((unsigned int)f2h(a[3] + bias[m].w) << 16);
                    *(uint2*)(vh + (size_t)(n * 16 + l15) * DH + m * 16 + quad * 4) = o;
                }
            if (tt == 0) {
                __syncthreads();
                pf_store_f32(pf, As);
                __syncthreads();
            }
        }
    } else {
        const int tb = (blockIdx.x - 340) * 2;
        // resident Wo|Wa fragments: m-tiles {3w, 3w+1, 3w+2}
        f16x8 aw[3][8];
#pragma unroll
        for (int m = 0; m < 3; m++)
#pragma unroll
            for (int kb = 0; kb < 8; kb++)
                aw[m][kb] = *(const f16x8*)(wsw + ((((w * 3 + m) * 8 + kb) << 9) + (lane << 3)));
        float4 bias[3];
#pragma unroll
        for (int m = 0; m < 3; m++) {
            const int mt = w * 3 + m;
            bias[m] = (mt < 16) ? *(const float4*)(bo + mt * 16 + quad * 4)
                                : *(const float4*)(ba + (mt - 16) * 16 + quad * 4);
        }

        stage_f32_512(query + (size_t)tb * 64 * 256, As);
        __syncthreads();
        float4 pf[8];
        pf_load_f32(query + (size_t)(tb + 1) * 64 * 256, pf);

#pragma unroll
        for (int tt = 0; tt < 2; tt++) {
            const size_t r0 = (size_t)(tb + tt) * 64;
            f32x4 acc[3][4];
#pragma unroll
            for (int m = 0; m < 3; m++)
#pragma unroll
                for (int n = 0; n < 4; n++) acc[m][n] = (f32x4){0.f, 0.f, 0.f, 0.f};
            mfma_resident<3>(As, aw, acc, lane);
#pragma unroll
            for (int m = 0; m < 3; m++) {
                const int mt = w * 3 + m;
                if (mt < 16) {
                    // offs -> locs. wcols c0..c0+3: xy=r&1, l fixed per lane.
                    const int c0 = mt * 16 + quad * 4;
                    const int l = (c0 >> 3) & 3;
                    const float rnorm = 1.f / (float)(128 >> l);
#pragma unroll
                    for (int n = 0; n < 4; n++) {
                        size_t row = r0 + n * 16 + l15;
                        float2 ref = *(const float2*)(refp + row * 8 + l * 2);
                        f32x4 a = acc[m][n];
                        float4 o;
                        o.x = ref.x + (a[0] + bias[m].x) * rnorm;
                        o.y = ref.y + (a[1] + bias[m].y) * rnorm;
                        o.z = ref.x + (a[2] + bias[m].z) * rnorm;
                        o.w = ref.y + (a[3] + bias[m].w) * rnorm;
                        *(float4*)(locs_ws + row * 256 + c0) = o;
                    }
                } else {
                    // attw: softmax over 16 lp = (quad x reg); h = mt-16.
                    const int c0 = (mt - 16) * 16 + quad * 4;
#pragma unroll
                    for (int n = 0; n < 4; n++) {
                        size_t row = r0 + n * 16 + l15;
                        f32x4 a = acc[m][n];
                        float v0 = a[0] + bias[m].x, v1 = a[1] + bias[m].y;
                        float v2 = a[2] + bias[m].z, v3 = a[3] + bias[m].w;
                        float mm = fmaxf(fmaxf(v0, v1), fmaxf(v2, v3));
                        mm = fmaxf(mm, __shfl_xor(mm, 16, 64));
                        mm = fmaxf(mm, __shfl_xor(mm, 32, 64));
                        float e0 = __expf(v0 - mm), e1 = __expf(v1 - mm);
                        float e2 = __expf(v2 - mm), e3 = __expf(v3 - mm);
                        float s = (e0 + e1) + (e2 + e3);
                        s += __shfl_xor(s, 16, 64);
                        s += __shfl_xor(s, 32, 64);
                        float rs = 1.f / s;
                        uint2 o;
                        o.x = (unsigned int)f2h(e0 * rs) | ((unsigned int)f2h(e1 * rs) << 16);
                        o.y = (unsigned int)f2h(e2 * rs) | ((unsigned int)f2h(e3 * rs) << 16);
                        *(uint2*)(attw_b + row * 128 + c0) = o;
                    }
                }
            }
            if (tt == 0) {
                __syncthreads();
                pf_store_f32(pf, As);
                __syncthreads();
            }
        }
    }
}

__device__ __forceinline__ void acc4(float wf, uint2 d,
                                     float& a0, float& a1, float& a2, float& a3)
{
    __half2 lo = *(__half2*)&d.x;
    __half2 hi = *(__half2*)&d.y;
    a0 = fmaf(wf, __half2float(__low2half(lo)),  a0);
    a1 = fmaf(wf, __half2float(__high2half(lo)), a1);
    a2 = fmaf(wf, __half2float(__low2half(hi)),  a2);
    a3 = fmaf(wf, __half2float(__high2half(hi)), a3);
}

// K2: fused tap-build + bilinear sampling (unchanged from r3 -- parked at its
// vector-memory plateau: 22.3M scattered 64B segments; VALU cuts r1-r3 all
// landed flat, so the bound is the gather path itself, not issue work).
__global__ __launch_bounds__(256) void k_sample(
    const unsigned short* __restrict__ v_hm,
    const float* __restrict__ locs_ws,
    const unsigned short* __restrict__ attw_b,
    unsigned short* __restrict__ msda_ws)
{
    __shared__ uint2 tap[16 * 4 * 32];   // [tp][corner][q] = {w_f32, pix*64}
    const int t = threadIdx.x;
    const int bid = blockIdx.x;

    const int xcd  = bid & 7;
    const int slot = bid >> 3;                 // [0,1360)
    const int sub  = (slot >= 680) ? 1 : 0;
    const int chunk = slot - sub * 680;        // [0,680)
    const int pair = xcd * 2 + sub;            // [0,16)
    const int b = pair & 1;
    const int h = pair >> 1;
    const int q0 = chunk * 32;

#pragma unroll
    for (int i = 0; i < 2; i++) {
        const int tapid = t + i * 256;         // [0,512)
        const int q  = tapid & 31;             // local q [0,32)
        const int tp = tapid >> 5;             // (l,p)
        const size_t row = (size_t)(b * NQ + q0 + q);
        float2 xy = *(const float2*)(locs_ws + row * 256 + h * 32 + tp * 2);
        float a   = h2f(attw_b[row * 128 + h * 16 + tp]);

        const int l = tp >> 2;
        const int Wl = 128 >> l;
        const float Wf = (float)Wl;
        const int start = (l == 0) ? 0 : (l == 1) ? 16384 : (l == 2) ? 20480 : 21504;
        float x = xy.x * Wf - 0.5f;
        float y = xy.y * Wf - 0.5f;
        float xf = floorf(x), yf = floorf(y);
        int x0 = (int)xf, y0 = (int)yf;
        float wx1 = x - xf, wy1 = y - yf;
        float wx0 = 1.f - wx1, wy0 = 1.f - wy1;
#pragma unroll
        for (int c = 0; c < 4; c++) {
            const int dx = c & 1, dy = c >> 1;
            int xi = x0 + dx, yi = y0 + dy;
            bool valid = (xi >= 0) & (xi < Wl) & (yi >= 0) & (yi < Wl);
            int xc = min(max(xi, 0), Wl - 1);
            int yc = min(max(yi, 0), Wl - 1);
            float wc = valid ? a * (dx ? wx1 : wx0) * (dy ? wy1 : wy0) : 0.f;
            uint2 rec;
            rec.x = __float_as_uint(wc);
            rec.y = ((unsigned int)(start + yc * Wl + xc)) * 64u;  // f16 row = 64 B
            tap[(tp * 4 + c) * 32 + q] = rec;
        }
    }
    __syncthreads();

    const int w4   = t >> 6;
    const int lane = t & 63;
    const int ql   = lane >> 3;
    const int c4   = lane & 7;
    const int q    = w4 * 8 + ql;
    const unsigned int c4off = (unsigned int)c4 * 8u;
    const char* __restrict__ vb =
        (const char*)(v_hm + (size_t)(b * NH + h) * NV * DH);

    float a0 = 0.f, a1 = 0.f, a2 = 0.f, a3 = 0.f;
#pragma unroll
    for (int ti = 0; ti < 16; ti++) {
        uint2 r0 = tap[(ti * 4 + 0) * 32 + q];
        uint2 r1 = tap[(ti * 4 + 1) * 32 + q];
        uint2 r2 = tap[(ti * 4 + 2) * 32 + q];
        uint2 r3 = tap[(ti * 4 + 3) * 32 + q];
        uint2 d0 = *(const uint2*)(vb + (r0.y + c4off));
        uint2 d1 = *(const uint2*)(vb + (r1.y + c4off));
        uint2 d2 = *(const uint2*)(vb + (r2.y + c4off));
        uint2 d3 = *(const uint2*)(vb + (r3.y + c4off));
        acc4(__uint_as_float(r0.x), d0, a0, a1, a2, a3);
        acc4(__uint_as_float(r1.x), d1, a0, a1, a2, a3);
        acc4(__uint_as_float(r2.x), d2, a0, a1, a2, a3);
        acc4(__uint_as_float(r3.x), d3, a0, a1, a2, a3);
    }
    uint2 o;
    o.x = (unsigned int)f2h(a0) | ((unsigned int)f2h(a1) << 16);
    o.y = (unsigned int)f2h(a2) | ((unsigned int)f2h(a3) << 16);
    *(uint2*)(msda_ws + (size_t)(b * NQ + q0 + q) * DIM + h * DH + c4 * 4) = o;
}

// K3: out = msda @ Wout + bout + query -> fp32. Persistent Wout (resident
// fragments, wave w -> wcols [w*32,(w+1)*32)), 340 blocks x 2 tiles, swapped
// operands -> float4 read-modify-write epilogue.
__global__ __launch_bounds__(512) void k_out_mfma(
    const unsigned short* __restrict__ msda_ws,
    const unsigned short* __restrict__ wswo,
    const float* __restrict__ bout,
    const float* __restrict__ query,
    float* __restrict__ out)
{
    __shared__ unsigned short As[64 * 264];
    const int t = threadIdx.x;
    const int w = t >> 6, lane = t & 63;
    const int quad = lane >> 4, l15 = lane & 15;
    const int tb = blockIdx.x * 2;

    f16x8 aw[2][8];
#pragma unroll
    for (int m = 0; m < 2; m++)
#pragma unroll
        for (int kb = 0; kb < 8; kb++)
            aw[m][kb] = *(const f16x8*)(wswo + ((((w * 2 + m) * 8 + kb) << 9) + (lane << 3)));
    float4 bias[2];
#pragma unroll
    for (int m = 0; m < 2; m++)
        bias[m] = *(const float4*)(bout + w * 32 + m * 16 + quad * 4);

    stage_h16_512(msda_ws + (size_t)tb * 64 * 256, As);
    __syncthreads();
    uint2 pf[8];
    pf_load_h16(msda_ws + (size_t)(tb + 1) * 64 * 256, pf);

#pragma unroll
    for (int tt = 0; tt < 2; tt++) {
        const size_t r0 = (size_t)(tb + tt) * 64;
        f32x4 acc[2][4];
#pragma unroll
        for (int m = 0; m < 2; m++)
#pragma unroll
            for (int n = 0; n < 4; n++) acc[m][n] = (f32x4){0.f, 0.f, 0.f, 0.f};
        mfma_resident<2>(As, aw, acc, lane);
#pragma unroll
        for (int m = 0; m < 2; m++) {
            const int c0 = w * 32 + m * 16 + quad * 4;
#pragma unroll
            for (int n = 0; n < 4; n++) {
                size_t row = r0 + n * 16 + l15;
                float4 q4 = *(const float4*)(query + row * 256 + c0);
                f32x4 a = acc[m][n];
                float4 o;
                o.x = a[0] + bias[m].x + q4.x;
                o.y = a[1] + bias[m].y + q4.y;
                o.z = a[2] + bias[m].z + q4.z;
                o.w = a[3] + bias[m].w + q4.w;
                *(float4*)(out + row * 256 + c0) = o;
            }
        }
        if (tt == 0) {
            __syncthreads();
            pf_store_h16(pf, As);
            __syncthreads();
        }
    }
}

extern "C" void kernel_launch(void* const* d_in, const int* in_sizes, int n_in,
                              void* d_out, int out_size, void* d_ws, size_t ws_size,
                              hipStream_t stream)
{
    const float* query = (const float*)d_in[0];
    const float* value = (const float*)d_in[1];
    const float* refp  = (const float*)d_in[2];
    // d_in[3] spatial_shapes, d_in[4] level_start_index : values hard-coded
    const float* Wv   = (const float*)d_in[5];
    const float* bv   = (const float*)d_in[6];
    const float* Wo   = (const float*)d_in[7];
    const float* bo   = (const float*)d_in[8];
    const float* Wa   = (const float*)d_in[9];
    const float* ba   = (const float*)d_in[10];
    const float* Wout = (const float*)d_in[11];
    const float* bout = (const float*)d_in[12];
    float* out = (float*)d_out;

    char* ws = (char*)d_ws;
    unsigned short* v_hm = (unsigned short*)ws;    ws += (size_t)BS * NH * NV * DH * 2; // 22.3 MB f16 head-major
    float* locs_ws = (float*)ws;                   ws += (size_t)BS * NQ * DIM * 4;     // 44.6 MB fp32
    unsigned short* attw_b = (unsigned short*)ws;  ws += (size_t)BS * NQ * 128 * 2;     // 11.1 MB f16
    unsigned short* msda_ws = (unsigned short*)ws; ws += (size_t)BS * NQ * DIM * 2;     // 22.3 MB f16
    unsigned short* wsw = (unsigned short*)ws;                                          // 448 KB

    k_wprep   <<<448, 64,  0, stream>>>(Wo, Wa, Wv, Wout, wsw);
    k_proj    <<<680, 512, 0, stream>>>(value, query, refp, wsw, bv, bo, ba,
                                        v_hm, locs_ws, attw_b);
    k_sample  <<<10880, 256, 0, stream>>>(v_hm, locs_ws, attw_b, msda_ws);
    k_out_mfma<<<340, 512, 0, stream>>>(msda_ws, wsw + 163840, bout, query, out);
}